// Round 1
// baseline (1968.805 us; speedup 1.0000x reference)
//
#include <hip/hip_runtime.h>
#include <math.h>

#define TB 256

constexpr int CBv = 16, CN = 4096, CHH = 8, CD = 64, CM = 128;
constexpr int V1P_OFF = CBv * CN * CHH * CD;            // 33554432 floats
constexpr int V2P_OFF = V1P_OFF + CBv * CN * CHH * CM;  // 100663296 floats
constexpr float KSCALE = 0.35355339059327373f;          // 64^-0.25 (tau=1)
constexpr float KRATIO = 0.08838834764831843f;          // 1/sqrt(128)
constexpr float KEPS   = 1e-6f;

__device__ __forceinline__ float dot4(float4 a, float4 b) {
  return fmaf(a.x, b.x, fmaf(a.y, b.y, fmaf(a.z, b.z, a.w * b.w)));
}
__device__ __forceinline__ float4 scl4(float4 a, float s) {
  return make_float4(a.x * s, a.y * s, a.z * s, a.w * s);
}
__device__ __forceinline__ void fma4(float4& a, float s, float4 b) {
  a.x = fmaf(s, b.x, a.x); a.y = fmaf(s, b.y, a.y);
  a.z = fmaf(s, b.z, a.z); a.w = fmaf(s, b.w, a.w);
}

// ---------------- K1: per-(b,h) max of key data_dash (partial per block) ----
__global__ __launch_bounds__(256, 2) void k1_maxdd(
    const float* __restrict__ nv2, const float* __restrict__ proj,
    float* __restrict__ partmax) {
  __shared__ float4 pj[2048];   // proj [128][64] f32 = 32KB
  __shared__ float red[256];
  const float4* pg = (const float4*)proj;
  for (int i = threadIdx.x; i < 2048; i += TB) pj[i] = pg[i];
  __syncthreads();
  const int bh = blockIdx.x >> 3, ch = blockIdx.x & 7;
  const int b = bh >> 3, h = bh & 7;
  const int n0 = ch * 512 + threadIdx.x;           // rows n0, n0+256
  const float4* a0 = (const float4*)(nv2 + ((b * CN + n0) * CHH + h) * CD);
  const float4* a1 = (const float4*)(nv2 + ((b * CN + n0 + 256) * CHH + h) * CD);
  float4 v0[16], v1[16];
#pragma unroll
  for (int q = 0; q < 16; q++) { v0[q] = scl4(a0[q], KSCALE); v1[q] = scl4(a1[q], KSCALE); }
  float mx = -1e30f;
  for (int j = 0; j < 128; j++) {
    const float4* p = &pj[j * 16];
    float s0 = 0.f, s1 = 0.f, s2 = 0.f, s3 = 0.f;
#pragma unroll
    for (int q = 0; q < 16; q += 2) {
      float4 pa = p[q], pb = p[q + 1];
      s0 += dot4(v0[q], pa); s1 += dot4(v0[q + 1], pb);
      s2 += dot4(v1[q], pa); s3 += dot4(v1[q + 1], pb);
    }
    mx = fmaxf(mx, fmaxf(s0 + s1, s2 + s3));
  }
  red[threadIdx.x] = mx;
  __syncthreads();
  for (int s = 128; s > 0; s >>= 1) {
    if ((int)threadIdx.x < s) red[threadIdx.x] = fmaxf(red[threadIdx.x], red[threadIdx.x + s]);
    __syncthreads();
  }
  if (threadIdx.x == 0) partmax[blockIdx.x] = red[0];
}

// ---------------- K1b: reduce 8 partials -> per-bh max ---------------------
__global__ void k1b_reduce(const float* __restrict__ partmax, float* __restrict__ wmax) {
  const int bh = threadIdx.x;  // 128 threads
  float m = -1e30f;
#pragma unroll
  for (int c = 0; c < 8; c++) m = fmaxf(m, partmax[bh * 8 + c]);
  wmax[bh] = m;
}

// ---------------- K2: v2p = ratio*(exp(dd - diag - mx_bh)+eps) -------------
__global__ __launch_bounds__(256, 2) void k2_v2p(
    const float* __restrict__ nv2, const float* __restrict__ proj,
    const float* __restrict__ wmax, float* __restrict__ v2p) {
  __shared__ float4 pj[2048];
  const float4* pg = (const float4*)proj;
  for (int i = threadIdx.x; i < 2048; i += TB) pj[i] = pg[i];
  __syncthreads();
  const int bh = blockIdx.x >> 3, ch = blockIdx.x & 7;
  const int b = bh >> 3, h = bh & 7;
  const int n0 = ch * 512 + threadIdx.x;
  const int r0 = (b * CN + n0) * CHH + h, r1 = (b * CN + n0 + 256) * CHH + h;
  const float4* a0 = (const float4*)(nv2 + r0 * CD);
  const float4* a1 = (const float4*)(nv2 + r1 * CD);
  float4 v0[16], v1[16];
#pragma unroll
  for (int q = 0; q < 16; q++) { v0[q] = scl4(a0[q], KSCALE); v1[q] = scl4(a1[q], KSCALE); }
  float d0 = 0.f, d1 = 0.f;
#pragma unroll
  for (int q = 0; q < 16; q++) { d0 += dot4(v0[q], v0[q]); d1 += dot4(v1[q], v1[q]); }
  const float mx = wmax[bh];
  const float c0 = -(0.5f * d0 + mx), c1 = -(0.5f * d1 + mx);
  float4* o0 = (float4*)(v2p + r0 * CM);
  float4* o1 = (float4*)(v2p + r1 * CM);
  for (int jq = 0; jq < 32; jq++) {
    float sa[4] = {0.f, 0.f, 0.f, 0.f}, sb[4] = {0.f, 0.f, 0.f, 0.f};
    const float4* p0 = &pj[(jq * 4 + 0) * 16];
    const float4* p1 = &pj[(jq * 4 + 1) * 16];
    const float4* p2 = &pj[(jq * 4 + 2) * 16];
    const float4* p3 = &pj[(jq * 4 + 3) * 16];
#pragma unroll
    for (int q = 0; q < 16; q++) {
      float4 t0 = p0[q], t1 = p1[q], t2 = p2[q], t3 = p3[q];
      sa[0] += dot4(v0[q], t0); sa[1] += dot4(v0[q], t1);
      sa[2] += dot4(v0[q], t2); sa[3] += dot4(v0[q], t3);
      sb[0] += dot4(v1[q], t0); sb[1] += dot4(v1[q], t1);
      sb[2] += dot4(v1[q], t2); sb[3] += dot4(v1[q], t3);
    }
    o0[jq] = make_float4(KRATIO * (__expf(sa[0] + c0) + KEPS), KRATIO * (__expf(sa[1] + c0) + KEPS),
                         KRATIO * (__expf(sa[2] + c0) + KEPS), KRATIO * (__expf(sa[3] + c0) + KEPS));
    o1[jq] = make_float4(KRATIO * (__expf(sb[0] + c1) + KEPS), KRATIO * (__expf(sb[1] + c1) + KEPS),
                         KRATIO * (__expf(sb[2] + c1) + KEPS), KRATIO * (__expf(sb[3] + c1) + KEPS));
  }
}

// ---------------- K3: partial v2x = v2p^T @ x (per bh, 8 chunks) -----------
__global__ __launch_bounds__(256, 4) void k3_v2x(
    const float* __restrict__ v2p, const float* __restrict__ x,
    float* __restrict__ part, float* __restrict__ vsumpart) {
  __shared__ float4 tv[1024];  // v2p tile [32 n][128 j]
  __shared__ float4 tx[512];   // x   tile [32 n][64 d]
  const int bh = blockIdx.x >> 3, ch = blockIdx.x & 7;
  const int b = bh >> 3, h = bh & 7;
  const int tj = threadIdx.x >> 3, td = threadIdx.x & 7;  // tj in [0,32), td in [0,8)
  float acc[4][8];
  float vs[4] = {0.f, 0.f, 0.f, 0.f};
#pragma unroll
  for (int i = 0; i < 4; i++)
#pragma unroll
    for (int k = 0; k < 8; k++) acc[i][k] = 0.f;
  for (int t0 = 0; t0 < 512; t0 += 32) {
    const int nb = ch * 512 + t0;
    __syncthreads();
    for (int q = threadIdx.x; q < 1024; q += TB) {
      int nn = q >> 5, c4 = q & 31;
      tv[q] = *((const float4*)(v2p + ((b * CN + nb + nn) * CHH + h) * CM) + c4);
    }
    for (int q = threadIdx.x; q < 512; q += TB) {
      int nn = q >> 4, c4 = q & 15;
      tx[q] = *((const float4*)(x + ((b * CN + nb + nn) * CHH + h) * CD) + c4);
    }
    __syncthreads();
    for (int nn = 0; nn < 32; nn++) {
      float4 aa = tv[nn * 32 + tj];
      float4 x0 = tx[nn * 16 + td * 2], x1 = tx[nn * 16 + td * 2 + 1];
      float av[4] = {aa.x, aa.y, aa.z, aa.w};
#pragma unroll
      for (int jj = 0; jj < 4; jj++) {
        acc[jj][0] = fmaf(av[jj], x0.x, acc[jj][0]);
        acc[jj][1] = fmaf(av[jj], x0.y, acc[jj][1]);
        acc[jj][2] = fmaf(av[jj], x0.z, acc[jj][2]);
        acc[jj][3] = fmaf(av[jj], x0.w, acc[jj][3]);
        acc[jj][4] = fmaf(av[jj], x1.x, acc[jj][4]);
        acc[jj][5] = fmaf(av[jj], x1.y, acc[jj][5]);
        acc[jj][6] = fmaf(av[jj], x1.z, acc[jj][6]);
        acc[jj][7] = fmaf(av[jj], x1.w, acc[jj][7]);
      }
      vs[0] += aa.x; vs[1] += aa.y; vs[2] += aa.z; vs[3] += aa.w;
    }
  }
  const int pbase = blockIdx.x * 8192;
#pragma unroll
  for (int jj = 0; jj < 4; jj++) {
    float4 w0 = make_float4(acc[jj][0], acc[jj][1], acc[jj][2], acc[jj][3]);
    float4 w1 = make_float4(acc[jj][4], acc[jj][5], acc[jj][6], acc[jj][7]);
    *(float4*)(part + pbase + (tj * 4 + jj) * 64 + td * 8) = w0;
    *(float4*)(part + pbase + (tj * 4 + jj) * 64 + td * 8 + 4) = w1;
  }
  if (td == 0) {
#pragma unroll
    for (int jj = 0; jj < 4; jj++) vsumpart[blockIdx.x * 128 + tj * 4 + jj] = vs[jj];
  }
}

// ---------------- K3b: reduce 8 partials -> v2x, v2sum ---------------------
__global__ void k3b_reduce(const float* __restrict__ part, const float* __restrict__ vsumpart,
                           float* __restrict__ v2x, float* __restrict__ vsum) {
  const int i = blockIdx.x * TB + threadIdx.x;  // grid covers 1048576 + 16384
  if (i < 1048576) {
    const int bh = i >> 13, r = i & 8191;
    float s = 0.f;
#pragma unroll
    for (int c = 0; c < 8; c++) s += part[((bh * 8 + c) << 13) + r];
    v2x[i] = s;
  } else {
    const int k = i - 1048576, bh = k >> 7, j = k & 127;
    float s = 0.f;
#pragma unroll
    for (int c = 0; c < 8; c++) s += vsumpart[((bh * 8 + c) << 7) + j];
    vsum[k] = s;
  }
}

// ---------------- K4a: v1p (row-local max), dd kept in 128 registers -------
__global__ __launch_bounds__(256, 2) void k4a_v1p(
    const float* __restrict__ nv1, const float* __restrict__ proj,
    float* __restrict__ v1p) {
  __shared__ float4 pj[2048];
  const float4* pg = (const float4*)proj;
  for (int i = threadIdx.x; i < 2048; i += TB) pj[i] = pg[i];
  __syncthreads();
  const int bh = blockIdx.x >> 4, ch = blockIdx.x & 15;
  const int b = bh >> 3, h = bh & 7;
  const int n = ch * 256 + threadIdx.x;
  const int r = (b * CN + n) * CHH + h;
  const float4* a = (const float4*)(nv1 + r * CD);
  float4 v[16];
#pragma unroll
  for (int q = 0; q < 16; q++) v[q] = scl4(a[q], KSCALE);
  float dsum = 0.f;
#pragma unroll
  for (int q = 0; q < 16; q++) dsum += dot4(v[q], v[q]);
  float4 dd[32];
#pragma unroll
  for (int jq = 0; jq < 32; jq++) {
    float s0 = 0.f, s1 = 0.f, s2 = 0.f, s3 = 0.f;
    const float4* p0 = &pj[(jq * 4 + 0) * 16];
    const float4* p1 = &pj[(jq * 4 + 1) * 16];
    const float4* p2 = &pj[(jq * 4 + 2) * 16];
    const float4* p3 = &pj[(jq * 4 + 3) * 16];
#pragma unroll
    for (int q = 0; q < 16; q++) {
      s0 += dot4(v[q], p0[q]); s1 += dot4(v[q], p1[q]);
      s2 += dot4(v[q], p2[q]); s3 += dot4(v[q], p3[q]);
    }
    dd[jq] = make_float4(s0, s1, s2, s3);
  }
  float mx = -1e30f;
#pragma unroll
  for (int jq = 0; jq < 32; jq++)
    mx = fmaxf(mx, fmaxf(fmaxf(dd[jq].x, dd[jq].y), fmaxf(dd[jq].z, dd[jq].w)));
  const float c = -(0.5f * dsum + mx);
  float4* o = (float4*)(v1p + r * CM);
#pragma unroll
  for (int jq = 0; jq < 32; jq++) {
    o[jq] = make_float4(KRATIO * (__expf(dd[jq].x + c) + KEPS), KRATIO * (__expf(dd[jq].y + c) + KEPS),
                        KRATIO * (__expf(dd[jq].z + c) + KEPS), KRATIO * (__expf(dd[jq].w + c) + KEPS));
  }
}

// ---------------- K4b: out0 = (v1p @ v2x) / (v1p . v2sum) ------------------
__global__ __launch_bounds__(256, 2) void k4b_out(
    const float* __restrict__ v1p, const float* __restrict__ v2xg,
    const float* __restrict__ vsumg, float* __restrict__ out0) {
  __shared__ float4 xv[2048];      // v2x [128][64]
  __shared__ float vsh[128];
  __shared__ float tp[16 * 260];   // v1p^T tile [16 j][256 rows], pad 260
  const int bh = blockIdx.x >> 4, ch = blockIdx.x & 15;
  const int b = bh >> 3, h = bh & 7;
  for (int i = threadIdx.x; i < 2048; i += TB) xv[i] = *((const float4*)v2xg + bh * 2048 + i);
  if (threadIdx.x < 128) vsh[threadIdx.x] = vsumg[bh * 128 + threadIdx.x];
  const int ng = threadIdx.x >> 2, dgi = threadIdx.x & 3;  // 64 row-groups x 4 d-groups
  const int n0 = ch * 256;
  float4 acc[4][4];
#pragma unroll
  for (int rr = 0; rr < 4; rr++)
#pragma unroll
    for (int k = 0; k < 4; k++) acc[rr][k] = make_float4(0.f, 0.f, 0.f, 0.f);
  float o2[4] = {0.f, 0.f, 0.f, 0.f};
  for (int jb = 0; jb < 8; jb++) {
    __syncthreads();
    for (int i = threadIdx.x; i < 1024; i += TB) {
      int row = i >> 2, c4 = i & 3;
      float4 t = *((const float4*)(v1p + ((b * CN + n0 + row) * CHH + h) * CM) + jb * 4 + c4);
      tp[(c4 * 4 + 0) * 260 + row] = t.x;
      tp[(c4 * 4 + 1) * 260 + row] = t.y;
      tp[(c4 * 4 + 2) * 260 + row] = t.z;
      tp[(c4 * 4 + 3) * 260 + row] = t.w;
    }
    __syncthreads();
#pragma unroll
    for (int jq = 0; jq < 4; jq++) {
#pragma unroll
      for (int u = 0; u < 4; u++) {
        const int j = jq * 4 + u;       // local j in [0,16)
        const int jg = jb * 16 + j;     // global j
        float4 x0 = xv[jg * 16 + dgi * 4 + 0];
        float4 x1 = xv[jg * 16 + dgi * 4 + 1];
        float4 x2 = xv[jg * 16 + dgi * 4 + 2];
        float4 x3 = xv[jg * 16 + dgi * 4 + 3];
        float vv = vsh[jg];
#pragma unroll
        for (int rr = 0; rr < 4; rr++) {
          float p = tp[j * 260 + ng * 4 + rr];
          fma4(acc[rr][0], p, x0);
          fma4(acc[rr][1], p, x1);
          fma4(acc[rr][2], p, x2);
          fma4(acc[rr][3], p, x3);
          o2[rr] = fmaf(p, vv, o2[rr]);
        }
      }
    }
  }
#pragma unroll
  for (int rr = 0; rr < 4; rr++) {
    const float inv = 1.0f / o2[rr];
    float* ob = out0 + ((b * CN + n0 + ng * 4 + rr) * CHH + h) * CD + dgi * 16;
    *(float4*)(ob + 0)  = scl4(acc[rr][0], inv);
    *(float4*)(ob + 4)  = scl4(acc[rr][1], inv);
    *(float4*)(ob + 8)  = scl4(acc[rr][2], inv);
    *(float4*)(ob + 12) = scl4(acc[rr][3], inv);
  }
}

extern "C" void kernel_launch(void* const* d_in, const int* in_sizes, int n_in,
                              void* d_out, int out_size, void* d_ws, size_t ws_size,
                              hipStream_t stream) {
  (void)in_sizes; (void)n_in; (void)out_size; (void)ws_size;
  const float* x    = (const float*)d_in[0];
  const float* nv1  = (const float*)d_in[1];
  const float* nv2  = (const float*)d_in[2];
  const float* proj = (const float*)d_in[3];
  float* out  = (float*)d_out;
  float* out0 = out;
  float* v1p  = out + V1P_OFF;
  float* v2p  = out + V2P_OFF;

  // Scratch inside the v1p output region (overwritten later by k4a):
  float* part     = v1p;             // 8,388,608 floats (k3 partials)
  float* partmax  = v1p + 8388608;   // 1,024
  float* vsumpart = v1p + 8389632;   // 131,072
  // Persistent scratch in ws (~4.3 MB): survives into k4a/k4b.
  float* ws   = (float*)d_ws;
  float* wmax = ws;                  // 128
  float* vsum = ws + 128;            // 16,384
  float* v2x  = ws + 16512;          // 1,048,576 (16B aligned)

  k1_maxdd <<<dim3(1024), dim3(256), 0, stream>>>(nv2, proj, partmax);
  k1b_reduce<<<dim3(1),   dim3(128), 0, stream>>>(partmax, wmax);
  k2_v2p   <<<dim3(1024), dim3(256), 0, stream>>>(nv2, proj, wmax, v2p);
  k3_v2x   <<<dim3(1024), dim3(256), 0, stream>>>(v2p, x, part, vsumpart);
  k3b_reduce<<<dim3(4160),dim3(256), 0, stream>>>(part, vsumpart, v2x, vsum);
  k4a_v1p  <<<dim3(2048), dim3(256), 0, stream>>>(nv1, proj, v1p);
  k4b_out  <<<dim3(2048), dim3(256), 0, stream>>>(v1p, v2x, vsum, out0);
}